// Round 7
// baseline (131.812 us; speedup 1.0000x reference)
//
#include <hip/hip_runtime.h>

// RecursiveNN: 11-level binary tree, shared linear map W(128x256)+b, bf16 MFMA.
// Evidence ledger (r0-r6): occupancy 3->4 neutral; gather-under-compute
// neutral; phase topology 17->13 neutral. Invariant across ALL variants:
// FETCH_SIZE 123 MB at 2.4-2.5 TB/s effective = dur. => tree128 is HBM-
// transfer-bound on the random embedding gather (scattered 512B rows reach
// ~40% of streaming BW). r3's "latency-bound" reading was a misparsed NaN
// FETCH row - retracted. Only lever: BYTES.
// This round: prep kernel converts emb fp32->bf16 (25.6 MB table in ws,
// streaming ~77MB ~14us, fused with pack_w) and tree128 gathers 256B bf16
// rows: compulsory gather bytes halve, table footprint L3-resident.
// Numerics identical (fp32->bf16 rounding happens before MFMA either way).
// ws_size guard: needs 27.8 MB; falls back to fp32 gather when short.
// LDS: 3 x 64-row STRIDE=136 buffers = 52224 B -> 3 blocks/CU, 0 conflicts.
// launch_bounds(256,3). Spill tripwire: WRITE_SIZE >> 2 MB.

typedef __bf16 bf16x8 __attribute__((ext_vector_type(8)));
typedef __bf16 bf16x4 __attribute__((ext_vector_type(4)));
typedef float f32x4 __attribute__((ext_vector_type(4)));

#define STRIDE 136  // 128 cols + 8 pad bf16 = 272B rows; 0 LDS conflicts measured

// prep: (1) blocks 0..15 pack W (fp32 128x256) into MFMA B-fragment lane order:
//   frag f=nl*8+kk, wave wv, lane l: elem j = W[o][d+j],
//   o=(2wv+nl)*16+(l&15), d=kk*32+(l>>4)*8; stored at wpack[(f*256+tid)*8].
// (2) all blocks grid-stride convert emb fp32 -> bf16 table (n8 x 8 elems).
__global__ void prep_kernel(const float* __restrict__ W,
                            const float* __restrict__ emb,
                            __bf16* __restrict__ wpack,
                            __bf16* __restrict__ etab, int n8) {
    const int tid = threadIdx.x;
    if (blockIdx.x < 16) {
        const int f = blockIdx.x;
        const int wv = tid >> 6, l = tid & 63;
        const int nl = f >> 3, kk = f & 7;
        const int o = ((wv << 1) + nl) * 16 + (l & 15);
        const int d = kk * 32 + ((l >> 4) << 3);
        const float* src = W + o * 256 + d;
        bf16x8 h;
#pragma unroll
        for (int j = 0; j < 8; ++j) h[j] = (__bf16)src[j];
        *(bf16x8*)(wpack + (size_t)(f * 256 + tid) * 8) = h;
    }
    const int stride = gridDim.x * blockDim.x;
    for (int i = blockIdx.x * blockDim.x + tid; i < n8; i += stride) {
        const float* s = emb + (size_t)i * 8;
        const f32x4 a = *(const f32x4*)s;
        const f32x4 b = *(const f32x4*)(s + 4);
        const bf16x4 ha = __builtin_convertvector(a, bf16x4);
        const bf16x4 hb = __builtin_convertvector(b, bf16x4);
        bf16x8 h;
#pragma unroll
        for (int j = 0; j < 4; ++j) { h[j] = ha[j]; h[4 + j] = hb[j]; }
        *(bf16x8*)(etab + (size_t)i * 8) = h;
    }
}

// Full-width level step: 64 input rows (src0=0..31, src1=32..63) -> 32 outputs.
// Both mt-tiles interleaved: 4 independent MFMA chains. Ends in barrier.
__device__ __forceinline__ void step32(
    const __bf16* src0, const __bf16* src1, __bf16* dst,
    const bf16x8* wf, const float* bval, int wv, int q, int lm)
{
    f32x4 acc[2][2];  // [mt][nl]
#pragma unroll
    for (int mt = 0; mt < 2; ++mt)
#pragma unroll
        for (int nl = 0; nl < 2; ++nl)
            acc[mt][nl] = f32x4{ bval[nl], bval[nl], bval[nl], bval[nl] };
#pragma unroll
    for (int kh = 0; kh < 2; ++kh) {            // K half: rows 2lm / 2lm+1
        const int row = 2 * lm + kh;
        bf16x8 a0[4], a1[4];
#pragma unroll
        for (int j = 0; j < 4; ++j) {
            a0[j] = *(const bf16x8*)&src0[row * STRIDE + j * 32 + q * 8];
            a1[j] = *(const bf16x8*)&src1[row * STRIDE + j * 32 + q * 8];
        }
#pragma unroll
        for (int j = 0; j < 4; ++j) {           // kk = kh*4+j: order 0..7 per acc
            acc[0][0] = __builtin_amdgcn_mfma_f32_16x16x32_bf16(
                a0[j], wf[0 * 8 + kh * 4 + j], acc[0][0], 0, 0, 0);
            acc[1][0] = __builtin_amdgcn_mfma_f32_16x16x32_bf16(
                a1[j], wf[0 * 8 + kh * 4 + j], acc[1][0], 0, 0, 0);
            acc[0][1] = __builtin_amdgcn_mfma_f32_16x16x32_bf16(
                a0[j], wf[1 * 8 + kh * 4 + j], acc[0][1], 0, 0, 0);
            acc[1][1] = __builtin_amdgcn_mfma_f32_16x16x32_bf16(
                a1[j], wf[1 * 8 + kh * 4 + j], acc[1][1], 0, 0, 0);
        }
    }
#pragma unroll
    for (int mt = 0; mt < 2; ++mt)
#pragma unroll
        for (int nl = 0; nl < 2; ++nl) {
            const int col = (2 * wv + nl) * 16 + lm;
            const bf16x4 hv = __builtin_convertvector(acc[mt][nl], bf16x4);
#pragma unroll
            for (int r = 0; r < 4; ++r)
                dst[(mt * 16 + q * 4 + r) * STRIDE + col] = hv[r];
        }
    __syncthreads();
}

// Small level step: NOUT (<=16) outputs from 2*NOUT input rows. Ends in barrier.
template <int NOUT>
__device__ __forceinline__ void step_small(
    const __bf16* src, __bf16* dst,
    const bf16x8* wf, const float* bval, int wv, int q, int lm)
{
    const int me = (NOUT >= 16) ? lm : (lm < NOUT ? lm : 0);
    f32x4 acc[2];
    acc[0] = f32x4{ bval[0], bval[0], bval[0], bval[0] };
    acc[1] = f32x4{ bval[1], bval[1], bval[1], bval[1] };
#pragma unroll
    for (int kh = 0; kh < 2; ++kh) {
        const int row = 2 * me + kh;
        bf16x8 af[4];
#pragma unroll
        for (int j = 0; j < 4; ++j)
            af[j] = *(const bf16x8*)&src[row * STRIDE + j * 32 + q * 8];
#pragma unroll
        for (int nl = 0; nl < 2; ++nl)
#pragma unroll
            for (int j = 0; j < 4; ++j)
                acc[nl] = __builtin_amdgcn_mfma_f32_16x16x32_bf16(
                    af[j], wf[nl * 8 + kh * 4 + j], acc[nl], 0, 0, 0);
    }
#pragma unroll
    for (int nl = 0; nl < 2; ++nl) {
        const int col = (2 * wv + nl) * 16 + lm;
        const bf16x4 hv = __builtin_convertvector(acc[nl], bf16x4);
#pragma unroll
        for (int r = 0; r < 4; ++r) {
            const int row = q * 4 + r;
            if (row < NOUT)
                dst[row * STRIDE + col] = hv[r];
        }
    }
    __syncthreads();
}

// Joint final: 8 input rows -> 4 roots (rows 0,1 = group A; 2,3 = group B)
// straight to global (bf16). No barrier.
__device__ __forceinline__ void final4(
    const __bf16* src, __bf16* yrow,
    const bf16x8* wf, const float* bval, int wv, int q, int lm)
{
    const int me = (lm < 4) ? lm : 0;
    f32x4 acc[2];
    acc[0] = f32x4{ bval[0], bval[0], bval[0], bval[0] };
    acc[1] = f32x4{ bval[1], bval[1], bval[1], bval[1] };
#pragma unroll
    for (int kh = 0; kh < 2; ++kh) {
        const int row = 2 * me + kh;
        bf16x8 af[4];
#pragma unroll
        for (int j = 0; j < 4; ++j)
            af[j] = *(const bf16x8*)&src[row * STRIDE + j * 32 + q * 8];
#pragma unroll
        for (int nl = 0; nl < 2; ++nl)
#pragma unroll
            for (int j = 0; j < 4; ++j)
                acc[nl] = __builtin_amdgcn_mfma_f32_16x16x32_bf16(
                    af[j], wf[nl * 8 + kh * 4 + j], acc[nl], 0, 0, 0);
    }
#pragma unroll
    for (int nl = 0; nl < 2; ++nl) {
        const int col = (2 * wv + nl) * 16 + lm;
        if (q == 0) {                 // rows 0..3 = quad 0 regs 0..3
#pragma unroll
            for (int r = 0; r < 4; ++r)
                yrow[r * 128 + col] = (__bf16)acc[nl][r];
        }
    }
}

// fp32 gather (fallback): 64 rows (512B each) into 32 staging VGPRs.
__device__ __forceinline__ void gather_issue_f32(
    const int* wb64, const float* emb, int tid, f32x4 (&s)[8])
{
#pragma unroll
    for (int i = 0; i < 8; ++i) {
        const int id = wb64[(tid >> 5) + 8 * i];
        s[i] = *(const f32x4*)(emb + (size_t)id * 128 + (tid & 31) * 4);
    }
}
__device__ __forceinline__ void gather_write_f32(
    __bf16* dst, int tid, const f32x4 (&s)[8])
{
#pragma unroll
    for (int i = 0; i < 8; ++i) {
        const int row = (tid >> 5) + 8 * i;
        *(bf16x4*)&dst[row * STRIDE + (tid & 31) * 4] =
            __builtin_convertvector(s[i], bf16x4);
    }
}

// bf16 gather (main path): 64 rows (256B each) into 16 staging VGPRs.
// 32 lanes x 8B = one row; half the HBM bytes of the fp32 path.
__device__ __forceinline__ void gather_issue_bf(
    const int* wb64, const __bf16* etab, int tid, bf16x4 (&s)[8])
{
#pragma unroll
    for (int i = 0; i < 8; ++i) {
        const int id = wb64[(tid >> 5) + 8 * i];
        s[i] = *(const bf16x4*)(etab + (size_t)id * 128 + (tid & 31) * 4);
    }
}
__device__ __forceinline__ void gather_write_bf(
    __bf16* dst, int tid, const bf16x4 (&s)[8])
{
#pragma unroll
    for (int i = 0; i < 8; ++i) {
        const int row = (tid >> 5) + 8 * i;
        *(bf16x4*)&dst[row * STRIDE + (tid & 31) * 4] = s[i];
    }
}

// Kernel 1: one block = 2 groups x 128 leaves (2048 blocks). Phases:
//  P0 prologue gather gA.h1->A; P1 issue gA.h2 | L1h1(gA) A->B[0:32];
//  P2 write h2->A; P3 issue gB.h1 | L1h2(gA) A->B[32:64];
//  P4 write gB.h1->A | L2(gA) B->D[0:32]; P5 issue gB.h2 | L1h1(gB);
//  P6 write h2->A; P7 L1h2(gB); P8 L2(gB) B->D[32:64];
//  P9 joint L3 D[0:64]->B[0:32]; P10 joint L4; P11 joint L5;
//  P12 joint final -> 4 root rows (gA:0,1 gB:2,3).
template <bool BF>
__global__ __launch_bounds__(256, 3) void tree128_kernel(
    const int* __restrict__ wid, const float* __restrict__ emb,
    const __bf16* __restrict__ etab, const __bf16* __restrict__ wpack,
    const float* __restrict__ bias, __bf16* __restrict__ yout)
{
    __shared__ __align__(16) __bf16 bufA[64 * STRIDE];  // 17408 B
    __shared__ __align__(16) __bf16 bufB[64 * STRIDE];  // 17408 B
    __shared__ __align__(16) __bf16 bufD[64 * STRIDE];  // 17408 B -> 52224 total
    const int tid = threadIdx.x;
    const int batch = blockIdx.x >> 3;   // 8 pairs (256 leaves each) per batch
    const int pair = blockIdx.x & 7;
    const int wv = tid >> 6, ln = tid & 63, q = ln >> 4, lm = ln & 15;

    // W fragments: 16 x (8 bf16) = 64 regs (AGPR-resident), coalesced 256B/thread.
    bf16x8 wf[16];
    const bf16x8* wp = (const bf16x8*)wpack;
#pragma unroll
    for (int f = 0; f < 16; ++f) wf[f] = wp[f * 256 + tid];
    float bval[2];
    bval[0] = bias[(2 * wv + 0) * 16 + lm];
    bval[1] = bias[(2 * wv + 1) * 16 + lm];

    const int* wb = wid + batch * 2048 + pair * 256;  // 256 leaves for this block
    f32x4 st32[8];   // staging (fp32 path, 32 VGPRs)
    bf16x4 st16[8];  // staging (bf16 path, 16 VGPRs); unused one is DCE'd

    auto issue = [&](const int* p) {
        if constexpr (BF) gather_issue_bf(p, etab, tid, st16);
        else              gather_issue_f32(p, emb, tid, st32);
    };
    auto write = [&](__bf16* d) {
        if constexpr (BF) gather_write_bf(d, tid, st16);
        else              gather_write_f32(d, tid, st32);
    };

    // P0: prologue (only exposed gather).
    issue(wb);
    write(bufA);
    __syncthreads();
    // P1
    issue(wb + 64);
    step32(bufA, bufA + 32 * STRIDE, bufB, wf, bval, wv, q, lm);
    // P2
    write(bufA);
    __syncthreads();
    // P3
    issue(wb + 128);
    step32(bufA, bufA + 32 * STRIDE, bufB + 32 * STRIDE, wf, bval, wv, q, lm);
    // P4: write gB.h1 under L2(gA); both covered by step32's end barrier.
    write(bufA);
    step32(bufB, bufB + 32 * STRIDE, bufD, wf, bval, wv, q, lm);
    // P5
    issue(wb + 192);
    step32(bufA, bufA + 32 * STRIDE, bufB, wf, bval, wv, q, lm);
    // P6
    write(bufA);
    __syncthreads();
    // P7
    step32(bufA, bufA + 32 * STRIDE, bufB + 32 * STRIDE, wf, bval, wv, q, lm);
    // P8
    step32(bufB, bufB + 32 * STRIDE, bufD + 32 * STRIDE, wf, bval, wv, q, lm);
    // P9: joint L3 (gA rows 0..31, gB rows 32..63)
    step32(bufD, bufD + 32 * STRIDE, bufB, wf, bval, wv, q, lm);
    // P10: joint L4
    step_small<16>(bufB, bufD, wf, bval, wv, q, lm);
    // P11: joint L5
    step_small<8>(bufD, bufB, wf, bval, wv, q, lm);
    // P12: joint final -> 4 root rows
    final4(bufB, yout + (size_t)(batch * 32 + pair * 4) * 128,
           wf, bval, wv, q, lm);
}

// Kernel 2: one block = one batch; 32 subtree roots -> 5 levels -> fp32 row.
__global__ __launch_bounds__(256) void tree32_kernel(
    const __bf16* __restrict__ yin, const __bf16* __restrict__ wpack,
    const float* __restrict__ bias, float* __restrict__ out)
{
    __shared__ __align__(16) __bf16 buf0[32 * STRIDE];  // 8704 B
    __shared__ __align__(16) __bf16 buf1[16 * STRIDE];  // 4352 B
    const int tid = threadIdx.x;
    const int batch = blockIdx.x;
    const int wv = tid >> 6, ln = tid & 63, q = ln >> 4, lm = ln & 15;

    bf16x8 wf[16];
    const bf16x8* wp = (const bf16x8*)wpack;
#pragma unroll
    for (int f = 0; f < 16; ++f) wf[f] = wp[f * 256 + tid];
    float bval[2];
    bval[0] = bias[(2 * wv + 0) * 16 + lm];
    bval[1] = bias[(2 * wv + 1) * 16 + lm];

#pragma unroll
    for (int i = 0; i < 2; ++i) {
        const int flat = tid + 256 * i;
        const int row = flat >> 4;
        const int c8 = flat & 15;
        const bf16x8 v =
            *(const bf16x8*)(yin + (size_t)(batch * 32 + row) * 128 + c8 * 8);
        *(bf16x8*)&buf0[row * STRIDE + c8 * 8] = v;
    }
    __syncthreads();

    step_small<16>(buf0, buf1, wf, bval, wv, q, lm);  // 32->16
    step_small<8> (buf1, buf0, wf, bval, wv, q, lm);  // 16->8
    step_small<4> (buf0, buf1, wf, bval, wv, q, lm);  // 8->4
    step_small<2> (buf1, buf0, wf, bval, wv, q, lm);  // 4->2

    // Final: rows 0,1 of buf0 -> root row (fp32 out).
    {
        f32x4 acc[2];
        acc[0] = f32x4{ bval[0], bval[0], bval[0], bval[0] };
        acc[1] = f32x4{ bval[1], bval[1], bval[1], bval[1] };
#pragma unroll
        for (int kh = 0; kh < 2; ++kh) {
            bf16x8 af[4];
#pragma unroll
            for (int j = 0; j < 4; ++j)
                af[j] = *(const bf16x8*)&buf0[kh * STRIDE + j * 32 + q * 8];
#pragma unroll
            for (int nl = 0; nl < 2; ++nl)
#pragma unroll
                for (int j = 0; j < 4; ++j)
                    acc[nl] = __builtin_amdgcn_mfma_f32_16x16x32_bf16(
                        af[j], wf[nl * 8 + kh * 4 + j], acc[nl], 0, 0, 0);
        }
#pragma unroll
        for (int nl = 0; nl < 2; ++nl) {
            const int col = (2 * wv + nl) * 16 + lm;
            if (q == 0) out[(size_t)batch * 128 + col] = acc[nl][0];
        }
    }
}

extern "C" void kernel_launch(void* const* d_in, const int* in_sizes, int n_in,
                              void* d_out, int out_size, void* d_ws, size_t ws_size,
                              hipStream_t stream) {
    const int*   wid = (const int*)d_in[0];      // (256, 2048) int32
    const float* emb = (const float*)d_in[1];    // (100000, 128) fp32
    const float* W   = (const float*)d_in[2];    // (128, 256) fp32
    const float* b   = (const float*)d_in[3];    // (128,) fp32
    float* out = (float*)d_out;                  // (256, 128) fp32

    __bf16* wpack = (__bf16*)d_ws;               // 32768 elems = 64 KB
    __bf16* y     = wpack + 32768;               // (256,32,128) bf16 = 2 MB
    __bf16* etab  = y + 256 * 32 * 128;          // (100000,128) bf16 = 25.6 MB

    const size_t need = (size_t)32768 * 2 + (size_t)256 * 32 * 128 * 2
                      + (size_t)100000 * 128 * 2;           // 27.76 MB
    const bool bf = (ws_size >= need);
    const int n8 = bf ? (100000 * 128 / 8) : 0;             // 1.6M cvt items

    prep_kernel<<<bf ? 2048 : 16, 256, 0, stream>>>(W, emb, wpack, etab, n8);
    if (bf)
        tree128_kernel<true><<<2048, 256, 0, stream>>>(
            wid, emb, etab, wpack, b, y);
    else
        tree128_kernel<false><<<2048, 256, 0, stream>>>(
            wid, emb, etab, wpack, b, y);
    tree32_kernel<<<256, 256, 0, stream>>>(y, wpack, b, out);
}

// Round 8
// 130.716 us; speedup vs baseline: 1.0084x; 1.0084x over previous
//
#include <hip/hip_runtime.h>

// RecursiveNN: 11-level binary tree, shared linear map W(128x256)+b, bf16 MFMA.
// Evidence ledger (r0-r7): occupancy 3->4 neutral; phase topology neutral;
// bf16 table halved FETCH (123->58MB) but dur only -13% and gather BW FELL
// 2.5->1.44 TB/s == exactly proportional to in-flight bytes/thread (fp32 8x16B
// vs bf16 8x8B). => gather is Little's-law-limited, and __syncthreads' implicit
// vmcnt(0) drain caps in-flight at ~one 64-row gather. This round: counted-vmcnt
// pipelining (T4):
//   (1) 16B gather loads (16 lanes x bf16x8 per 256B row),
//   (2) 2-deep rolling issue (2 gathers staged in regs, issue->write >= 3
//       barriers ~1500cyc > 900cyc HBM latency), ids preloaded to regs,
//   (3) raw barriers {s_waitcnt lgkmcnt(0); s_barrier} that do NOT drain vmcnt;
//       compiler's per-use counted vmcnt waits handle staging-reg consumption.
// prep converts emb fp32->bf16 (25.6MB, ~13us streaming) - kept from r7.
// LDS: A/B/D 64-row STRIDE=136 buffers = 52224 B -> 3 blocks/CU, 0 conflicts.
// launch_bounds(256,3). Spill tripwire: WRITE_SIZE >> 2 MB.

typedef __bf16 bf16x8 __attribute__((ext_vector_type(8)));
typedef __bf16 bf16x4 __attribute__((ext_vector_type(4)));
typedef float f32x4 __attribute__((ext_vector_type(4)));

#define STRIDE 136  // 128 cols + 8 pad bf16 = 272B rows; 0 LDS conflicts measured

// Raw barrier: orders LDS ops across threads WITHOUT draining vmcnt (in-flight
// global gathers survive). "memory" clobber pins C-level ds ops to their side.
#define BARRIER() do {                                          \
    asm volatile("s_waitcnt lgkmcnt(0)" ::: "memory");          \
    __builtin_amdgcn_s_barrier();                               \
} while (0)

// prep: (1) blocks 0..15 pack W (fp32 128x256) into MFMA B-fragment lane order:
//   frag f=nl*8+kk, wave wv, lane l: elem j = W[o][d+j],
//   o=(2wv+nl)*16+(l&15), d=kk*32+(l>>4)*8; stored at wpack[(f*256+tid)*8].
// (2) all blocks grid-stride convert emb fp32 -> bf16 table (n8 x 8 elems).
__global__ void prep_kernel(const float* __restrict__ W,
                            const float* __restrict__ emb,
                            __bf16* __restrict__ wpack,
                            __bf16* __restrict__ etab, int n8) {
    const int tid = threadIdx.x;
    if (blockIdx.x < 16) {
        const int f = blockIdx.x;
        const int wv = tid >> 6, l = tid & 63;
        const int nl = f >> 3, kk = f & 7;
        const int o = ((wv << 1) + nl) * 16 + (l & 15);
        const int d = kk * 32 + ((l >> 4) << 3);
        const float* src = W + o * 256 + d;
        bf16x8 h;
#pragma unroll
        for (int j = 0; j < 8; ++j) h[j] = (__bf16)src[j];
        *(bf16x8*)(wpack + (size_t)(f * 256 + tid) * 8) = h;
    }
    const int stride = gridDim.x * blockDim.x;
    for (int i = blockIdx.x * blockDim.x + tid; i < n8; i += stride) {
        const float* s = emb + (size_t)i * 8;
        const f32x4 a = *(const f32x4*)s;
        const f32x4 b = *(const f32x4*)(s + 4);
        const bf16x4 ha = __builtin_convertvector(a, bf16x4);
        const bf16x4 hb = __builtin_convertvector(b, bf16x4);
        bf16x8 h;
#pragma unroll
        for (int j = 0; j < 4; ++j) { h[j] = ha[j]; h[4 + j] = hb[j]; }
        *(bf16x8*)(etab + (size_t)i * 8) = h;
    }
}

// Full-width level step: 64 input rows (src0=0..31, src1=32..63) -> 32 outputs.
// Both mt-tiles interleaved: 4 independent MFMA chains. NO barrier (caller's).
__device__ __forceinline__ void step32(
    const __bf16* src0, const __bf16* src1, __bf16* dst,
    const bf16x8* wf, const float* bval, int wv, int q, int lm)
{
    f32x4 acc[2][2];  // [mt][nl]
#pragma unroll
    for (int mt = 0; mt < 2; ++mt)
#pragma unroll
        for (int nl = 0; nl < 2; ++nl)
            acc[mt][nl] = f32x4{ bval[nl], bval[nl], bval[nl], bval[nl] };
#pragma unroll
    for (int kh = 0; kh < 2; ++kh) {            // K half: rows 2lm / 2lm+1
        const int row = 2 * lm + kh;
        bf16x8 a0[4], a1[4];
#pragma unroll
        for (int j = 0; j < 4; ++j) {
            a0[j] = *(const bf16x8*)&src0[row * STRIDE + j * 32 + q * 8];
            a1[j] = *(const bf16x8*)&src1[row * STRIDE + j * 32 + q * 8];
        }
#pragma unroll
        for (int j = 0; j < 4; ++j) {           // kk = kh*4+j: order 0..7 per acc
            acc[0][0] = __builtin_amdgcn_mfma_f32_16x16x32_bf16(
                a0[j], wf[0 * 8 + kh * 4 + j], acc[0][0], 0, 0, 0);
            acc[1][0] = __builtin_amdgcn_mfma_f32_16x16x32_bf16(
                a1[j], wf[0 * 8 + kh * 4 + j], acc[1][0], 0, 0, 0);
            acc[0][1] = __builtin_amdgcn_mfma_f32_16x16x32_bf16(
                a0[j], wf[1 * 8 + kh * 4 + j], acc[0][1], 0, 0, 0);
            acc[1][1] = __builtin_amdgcn_mfma_f32_16x16x32_bf16(
                a1[j], wf[1 * 8 + kh * 4 + j], acc[1][1], 0, 0, 0);
        }
    }
#pragma unroll
    for (int mt = 0; mt < 2; ++mt)
#pragma unroll
        for (int nl = 0; nl < 2; ++nl) {
            const int col = (2 * wv + nl) * 16 + lm;
            const bf16x4 hv = __builtin_convertvector(acc[mt][nl], bf16x4);
#pragma unroll
            for (int r = 0; r < 4; ++r)
                dst[(mt * 16 + q * 4 + r) * STRIDE + col] = hv[r];
        }
}

// Small level step: NOUT (<=16) outputs from 2*NOUT input rows. NO barrier.
template <int NOUT>
__device__ __forceinline__ void step_small(
    const __bf16* src, __bf16* dst,
    const bf16x8* wf, const float* bval, int wv, int q, int lm)
{
    const int me = (NOUT >= 16) ? lm : (lm < NOUT ? lm : 0);
    f32x4 acc[2];
    acc[0] = f32x4{ bval[0], bval[0], bval[0], bval[0] };
    acc[1] = f32x4{ bval[1], bval[1], bval[1], bval[1] };
#pragma unroll
    for (int kh = 0; kh < 2; ++kh) {
        const int row = 2 * me + kh;
        bf16x8 af[4];
#pragma unroll
        for (int j = 0; j < 4; ++j)
            af[j] = *(const bf16x8*)&src[row * STRIDE + j * 32 + q * 8];
#pragma unroll
        for (int nl = 0; nl < 2; ++nl)
#pragma unroll
            for (int j = 0; j < 4; ++j)
                acc[nl] = __builtin_amdgcn_mfma_f32_16x16x32_bf16(
                    af[j], wf[nl * 8 + kh * 4 + j], acc[nl], 0, 0, 0);
    }
#pragma unroll
    for (int nl = 0; nl < 2; ++nl) {
        const int col = (2 * wv + nl) * 16 + lm;
        const bf16x4 hv = __builtin_convertvector(acc[nl], bf16x4);
#pragma unroll
        for (int r = 0; r < 4; ++r) {
            const int row = q * 4 + r;
            if (row < NOUT)
                dst[row * STRIDE + col] = hv[r];
        }
    }
}

// Joint final: 8 input rows -> 4 roots (rows 0,1 = group A; 2,3 = group B)
// straight to global (bf16). No barrier.
__device__ __forceinline__ void final4(
    const __bf16* src, __bf16* yrow,
    const bf16x8* wf, const float* bval, int wv, int q, int lm)
{
    const int me = (lm < 4) ? lm : 0;
    f32x4 acc[2];
    acc[0] = f32x4{ bval[0], bval[0], bval[0], bval[0] };
    acc[1] = f32x4{ bval[1], bval[1], bval[1], bval[1] };
#pragma unroll
    for (int kh = 0; kh < 2; ++kh) {
        const int row = 2 * me + kh;
        bf16x8 af[4];
#pragma unroll
        for (int j = 0; j < 4; ++j)
            af[j] = *(const bf16x8*)&src[row * STRIDE + j * 32 + q * 8];
#pragma unroll
        for (int nl = 0; nl < 2; ++nl)
#pragma unroll
            for (int j = 0; j < 4; ++j)
                acc[nl] = __builtin_amdgcn_mfma_f32_16x16x32_bf16(
                    af[j], wf[nl * 8 + kh * 4 + j], acc[nl], 0, 0, 0);
    }
#pragma unroll
    for (int nl = 0; nl < 2; ++nl) {
        const int col = (2 * wv + nl) * 16 + lm;
        if (q == 0) {                 // rows 0..3 = quad 0 regs 0..3
#pragma unroll
            for (int r = 0; r < 4; ++r)
                yrow[r * 128 + col] = (__bf16)acc[nl][r];
        }
    }
}

// bf16 wide gather: 64 rows, 16 lanes x 16B per row; thread covers rows
// (tid>>4)+16i. Issue fills 16 staging VGPRs (4 x bf16x8); ids pre-loaded.
__device__ __forceinline__ void gissue_bf(
    const int (&ids)[4], const __bf16* etab, int tid, bf16x8 (&s)[4])
{
#pragma unroll
    for (int i = 0; i < 4; ++i)
        s[i] = *(const bf16x8*)(etab + (size_t)ids[i] * 128 + (tid & 15) * 8);
}
__device__ __forceinline__ void gwrite_bf(
    __bf16* dst, int tid, const bf16x8 (&s)[4])
{
#pragma unroll
    for (int i = 0; i < 4; ++i) {
        const int row = (tid >> 4) + 16 * i;
        *(bf16x8*)&dst[row * STRIDE + (tid & 15) * 8] = s[i];
    }
}

// fp32 fallback gather (r6 behavior): 64 rows, 32 lanes x 16B.
__device__ __forceinline__ void gissue_f32(
    const int* wb64, const float* emb, int tid, f32x4 (&s)[8])
{
#pragma unroll
    for (int i = 0; i < 8; ++i) {
        const int id = wb64[(tid >> 5) + 8 * i];
        s[i] = *(const f32x4*)(emb + (size_t)id * 128 + (tid & 31) * 4);
    }
}
__device__ __forceinline__ void gwrite_f32(
    __bf16* dst, int tid, const f32x4 (&s)[8])
{
#pragma unroll
    for (int i = 0; i < 8; ++i) {
        const int row = (tid >> 5) + 8 * i;
        *(bf16x4*)&dst[row * STRIDE + (tid & 31) * 4] =
            __builtin_convertvector(s[i], bf16x4);
    }
}

// Kernel 1: one block = 2 groups x 128 leaves (2048 blocks).
// bf16 path schedule (2-deep rolling gather, raw barriers):
//  pre: issue G0(g0h1)->s1, G1(g0h2)->s2        [8x16B in flight]
//  P0: write s1->A; BAR                          (vmcnt waits s1 only)
//  P1: issue G2(g1h1)->s1 | L1h1(gA) A->B[0:32]; BAR
//  P2: write s2->A; BAR
//  P3: issue G3(g1h2)->s2 | L1h2(gA) A->B[32:64]; BAR
//  P4: write s1->A | L2(gA) B->D[0:32]; BAR      (s1 issued P1: 3 BARs ago)
//  P5: L1h1(gB) A->B[0:32]; BAR
//  P6: write s2->A; BAR
//  P7: L1h2(gB) A->B[32:64]; BAR
//  P8: L2(gB) B->D[32:64]; BAR
//  P9: joint L3 D->B[0:32]; BAR  P10: L4; BAR  P11: L5; BAR
//  P12: joint final -> 4 root rows (gA:0,1 gB:2,3)
template <bool BF>
__global__ __launch_bounds__(256, 3) void tree128_kernel(
    const int* __restrict__ wid, const float* __restrict__ emb,
    const __bf16* __restrict__ etab, const __bf16* __restrict__ wpack,
    const float* __restrict__ bias, __bf16* __restrict__ yout)
{
    __shared__ __align__(16) __bf16 bufA[64 * STRIDE];  // 17408 B
    __shared__ __align__(16) __bf16 bufB[64 * STRIDE];  // 17408 B
    __shared__ __align__(16) __bf16 bufD[64 * STRIDE];  // 17408 B -> 52224 total
    const int tid = threadIdx.x;
    const int batch = blockIdx.x >> 3;   // 8 pairs (256 leaves each) per batch
    const int pair = blockIdx.x & 7;
    const int wv = tid >> 6, ln = tid & 63, q = ln >> 4, lm = ln & 15;

    // W fragments: 16 x (8 bf16) = 64 regs (AGPR-resident), coalesced 256B/thread.
    bf16x8 wf[16];
    const bf16x8* wp = (const bf16x8*)wpack;
#pragma unroll
    for (int f = 0; f < 16; ++f) wf[f] = wp[f * 256 + tid];
    float bval[2];
    bval[0] = bias[(2 * wv + 0) * 16 + lm];
    bval[1] = bias[(2 * wv + 1) * 16 + lm];

    const int* wb = wid + batch * 2048 + pair * 256;  // 256 leaves for this block

    if constexpr (BF) {
        // Preload all 16 leaf ids (4 gathers x 4 rows/thread): no id-latency
        // on the critical issue path. 16 lanes share each id (broadcast).
        int ids[4][4];
#pragma unroll
        for (int g = 0; g < 4; ++g)
#pragma unroll
            for (int i = 0; i < 4; ++i)
                ids[g][i] = wb[g * 64 + (tid >> 4) + 16 * i];

        bf16x8 s1[4], s2[4];  // 2-deep staging: 32 VGPRs
        gissue_bf(ids[0], etab, tid, s1);
        gissue_bf(ids[1], etab, tid, s2);
        // P0
        gwrite_bf(bufA, tid, s1);
        BARRIER();
        // P1
        gissue_bf(ids[2], etab, tid, s1);
        step32(bufA, bufA + 32 * STRIDE, bufB, wf, bval, wv, q, lm);
        BARRIER();
        // P2
        gwrite_bf(bufA, tid, s2);
        BARRIER();
        // P3
        gissue_bf(ids[3], etab, tid, s2);
        step32(bufA, bufA + 32 * STRIDE, bufB + 32 * STRIDE, wf, bval, wv, q, lm);
        BARRIER();
        // P4
        gwrite_bf(bufA, tid, s1);
        step32(bufB, bufB + 32 * STRIDE, bufD, wf, bval, wv, q, lm);
        BARRIER();
        // P5
        step32(bufA, bufA + 32 * STRIDE, bufB, wf, bval, wv, q, lm);
        BARRIER();
        // P6
        gwrite_bf(bufA, tid, s2);
        BARRIER();
        // P7
        step32(bufA, bufA + 32 * STRIDE, bufB + 32 * STRIDE, wf, bval, wv, q, lm);
        BARRIER();
    } else {
        // Fallback (r6 behavior, fp32 gather, 1-deep).
        f32x4 st[8];
        gissue_f32(wb, emb, tid, st);
        gwrite_f32(bufA, tid, st);
        BARRIER();
        gissue_f32(wb + 64, emb, tid, st);
        step32(bufA, bufA + 32 * STRIDE, bufB, wf, bval, wv, q, lm);
        BARRIER();
        gwrite_f32(bufA, tid, st);
        BARRIER();
        gissue_f32(wb + 128, emb, tid, st);
        step32(bufA, bufA + 32 * STRIDE, bufB + 32 * STRIDE, wf, bval, wv, q, lm);
        BARRIER();
        gwrite_f32(bufA, tid, st);
        step32(bufB, bufB + 32 * STRIDE, bufD, wf, bval, wv, q, lm);
        BARRIER();
        step32(bufA, bufA + 32 * STRIDE, bufB, wf, bval, wv, q, lm);
        BARRIER();
        gissue_f32(wb + 192, emb, tid, st);
        gwrite_f32(bufA, tid, st);
        BARRIER();
        step32(bufA, bufA + 32 * STRIDE, bufB + 32 * STRIDE, wf, bval, wv, q, lm);
        BARRIER();
    }
    // P8
    step32(bufB, bufB + 32 * STRIDE, bufD + 32 * STRIDE, wf, bval, wv, q, lm);
    BARRIER();
    // P9: joint L3 (gA rows 0..31, gB rows 32..63)
    step32(bufD, bufD + 32 * STRIDE, bufB, wf, bval, wv, q, lm);
    BARRIER();
    // P10: joint L4
    step_small<16>(bufB, bufD, wf, bval, wv, q, lm);
    BARRIER();
    // P11: joint L5
    step_small<8>(bufD, bufB, wf, bval, wv, q, lm);
    BARRIER();
    // P12: joint final -> 4 root rows
    final4(bufB, yout + (size_t)(batch * 32 + pair * 4) * 128,
           wf, bval, wv, q, lm);
}

// Kernel 2: one block = one batch; 32 subtree roots -> 5 levels -> fp32 row.
__global__ __launch_bounds__(256) void tree32_kernel(
    const __bf16* __restrict__ yin, const __bf16* __restrict__ wpack,
    const float* __restrict__ bias, float* __restrict__ out)
{
    __shared__ __align__(16) __bf16 buf0[32 * STRIDE];  // 8704 B
    __shared__ __align__(16) __bf16 buf1[16 * STRIDE];  // 4352 B
    const int tid = threadIdx.x;
    const int batch = blockIdx.x;
    const int wv = tid >> 6, ln = tid & 63, q = ln >> 4, lm = ln & 15;

    bf16x8 wf[16];
    const bf16x8* wp = (const bf16x8*)wpack;
#pragma unroll
    for (int f = 0; f < 16; ++f) wf[f] = wp[f * 256 + tid];
    float bval[2];
    bval[0] = bias[(2 * wv + 0) * 16 + lm];
    bval[1] = bias[(2 * wv + 1) * 16 + lm];

#pragma unroll
    for (int i = 0; i < 2; ++i) {
        const int flat = tid + 256 * i;
        const int row = flat >> 4;
        const int c8 = flat & 15;
        const bf16x8 v =
            *(const bf16x8*)(yin + (size_t)(batch * 32 + row) * 128 + c8 * 8);
        *(bf16x8*)&buf0[row * STRIDE + c8 * 8] = v;
    }
    __syncthreads();

    step_small<16>(buf0, buf1, wf, bval, wv, q, lm);  __syncthreads();
    step_small<8> (buf1, buf0, wf, bval, wv, q, lm);  __syncthreads();
    step_small<4> (buf0, buf1, wf, bval, wv, q, lm);  __syncthreads();
    step_small<2> (buf1, buf0, wf, bval, wv, q, lm);  __syncthreads();

    // Final: rows 0,1 of buf0 -> root row (fp32 out).
    {
        f32x4 acc[2];
        acc[0] = f32x4{ bval[0], bval[0], bval[0], bval[0] };
        acc[1] = f32x4{ bval[1], bval[1], bval[1], bval[1] };
#pragma unroll
        for (int kh = 0; kh < 2; ++kh) {
            bf16x8 af[4];
#pragma unroll
            for (int j = 0; j < 4; ++j)
                af[j] = *(const bf16x8*)&buf0[kh * STRIDE + j * 32 + q * 8];
#pragma unroll
            for (int nl = 0; nl < 2; ++nl)
#pragma unroll
                for (int j = 0; j < 4; ++j)
                    acc[nl] = __builtin_amdgcn_mfma_f32_16x16x32_bf16(
                        af[j], wf[nl * 8 + kh * 4 + j], acc[nl], 0, 0, 0);
        }
#pragma unroll
        for (int nl = 0; nl < 2; ++nl) {
            const int col = (2 * wv + nl) * 16 + lm;
            if (q == 0) out[(size_t)batch * 128 + col] = acc[nl][0];
        }
    }
}

extern "C" void kernel_launch(void* const* d_in, const int* in_sizes, int n_in,
                              void* d_out, int out_size, void* d_ws, size_t ws_size,
                              hipStream_t stream) {
    const int*   wid = (const int*)d_in[0];      // (256, 2048) int32
    const float* emb = (const float*)d_in[1];    // (100000, 128) fp32
    const float* W   = (const float*)d_in[2];    // (128, 256) fp32
    const float* b   = (const float*)d_in[3];    // (128,) fp32
    float* out = (float*)d_out;                  // (256, 128) fp32

    __bf16* wpack = (__bf16*)d_ws;               // 32768 elems = 64 KB
    __bf16* y     = wpack + 32768;               // (256,32,128) bf16 = 2 MB
    __bf16* etab  = y + 256 * 32 * 128;          // (100000,128) bf16 = 25.6 MB

    const size_t need = (size_t)32768 * 2 + (size_t)256 * 32 * 128 * 2
                      + (size_t)100000 * 128 * 2;           // 27.76 MB
    const bool bf = (ws_size >= need);
    const int n8 = bf ? (100000 * 128 / 8) : 0;             // 1.6M cvt items

    prep_kernel<<<bf ? 2048 : 16, 256, 0, stream>>>(W, emb, wpack, etab, n8);
    if (bf)
        tree128_kernel<true><<<2048, 256, 0, stream>>>(
            wid, emb, etab, wpack, b, y);
    else
        tree128_kernel<false><<<2048, 256, 0, stream>>>(
            wid, emb, etab, wpack, b, y);
    tree32_kernel<<<256, 256, 0, stream>>>(y, wpack, b, out);
}